// Round 1
// baseline (766.198 us; speedup 1.0000x reference)
//
#include <hip/hip_runtime.h>

// MoV3D: 3D local attention, window +-2 (125 offsets), B=2 C=32 H=W=D=48, 4 heads x 8 ch.
// out[b][d][x][y][z] = mean_h sum_n softmax_n(score)_n * offset_d(n)
// One thread per voxel; all 4 heads per thread; no-max softmax (safe: scores bounded,
// OOB offsets contribute exactly 0 weight, matching reference's -1000 -> exp underflow).

#define S_PLANE 2304      // 48*48
#define S_CHAN 110592     // 48*48*48
#define NC 32
#define NH 4
#define HD 8

__global__ __launch_bounds__(256) void mov3d_kernel(
    const float* __restrict__ xq, const float* __restrict__ xk,
    float* __restrict__ out)
{
    int idx = blockIdx.x * 256 + threadIdx.x;   // 0..221183
    int z = idx % 48;
    int t = idx / 48;
    int y = t % 48;
    t /= 48;
    int x = t % 48;
    int b = t / 48;

    unsigned boff = (unsigned)b * (NC * S_CHAN);
    unsigned sp = (unsigned)(x * S_PLANE + y * 48 + z);

    const float scale = 0.35355339059327373f; // 8^-0.5

    float q[NC];
#pragma unroll
    for (int c = 0; c < NC; ++c)
        q[c] = xq[boff + (unsigned)(c * S_CHAN) + sp] * scale;

    // per-thread z clamp table (5 slots)
    int zc[5]; bool vz[5];
#pragma unroll
    for (int j = 0; j < 5; ++j) {
        int zz = z + j - 2;
        vz[j] = (zz >= 0 && zz < 48);
        zc[j] = min(max(zz, 0), 47);
    }

    float l[NH]  = {0.f, 0.f, 0.f, 0.f};
    float ax[NH] = {0.f, 0.f, 0.f, 0.f};
    float ay[NH] = {0.f, 0.f, 0.f, 0.f};
    float az[NH] = {0.f, 0.f, 0.f, 0.f};

    for (int dx = -2; dx <= 2; ++dx) {
        int xx = x + dx;
        bool vx = (xx >= 0) && (xx < 48);
        int xcl = min(max(xx, 0), 47);
        for (int dy = -2; dy <= 2; ++dy) {
            int yy = y + dy;
            bool vxy = vx && (yy >= 0) && (yy < 48);
            int ycl = min(max(yy, 0), 47);
            unsigned rb = boff + (unsigned)(xcl * S_PLANE + ycl * 48);
            unsigned off[5];
#pragma unroll
            for (int j = 0; j < 5; ++j) off[j] = rb + (unsigned)zc[j];

            float s[NH][5];
#pragma unroll
            for (int h = 0; h < NH; ++h)
#pragma unroll
                for (int j = 0; j < 5; ++j) s[h][j] = 0.f;

#pragma unroll
            for (int ch = 0; ch < HD; ++ch) {
#pragma unroll
                for (int h = 0; h < NH; ++h) {
                    const int c = ch * NH + h;         // channel owned by head h
                    float qv = q[c];
                    const unsigned cb = (unsigned)(c * S_CHAN);
#pragma unroll
                    for (int j = 0; j < 5; ++j) {
                        s[h][j] = fmaf(qv, xk[cb + off[j]], s[h][j]);
                    }
                }
            }

            // accumulate un-normalized softmax + weighted offsets
#pragma unroll
            for (int h = 0; h < NH; ++h) {
#pragma unroll
                for (int j = 0; j < 5; ++j) {
                    bool v = vxy && vz[j];
                    float w = v ? __expf(s[h][j]) : 0.f;
                    l[h]  += w;
                    ax[h] += w * (float)dx;
                    ay[h] += w * (float)dy;
                    az[h] += w * (float)(j - 2);
                }
            }
        }
    }

    float ox = 0.f, oy = 0.f, oz = 0.f;
#pragma unroll
    for (int h = 0; h < NH; ++h) {
        float r = 1.0f / l[h];
        ox += ax[h] * r;
        oy += ay[h] * r;
        oz += az[h] * r;
    }
    unsigned ob = (unsigned)b * (3 * S_CHAN);
    out[ob + 0u * S_CHAN + sp] = ox * 0.25f;
    out[ob + 1u * S_CHAN + sp] = oy * 0.25f;
    out[ob + 2u * S_CHAN + sp] = oz * 0.25f;
}

extern "C" void kernel_launch(void* const* d_in, const int* in_sizes, int n_in,
                              void* d_out, int out_size, void* d_ws, size_t ws_size,
                              hipStream_t stream) {
    const float* xq = (const float*)d_in[0];
    const float* xk = (const float*)d_in[1];
    float* out = (float*)d_out;
    // B*H*W*D = 2*48*48*48 = 221184 = 864 * 256
    mov3d_kernel<<<864, 256, 0, stream>>>(xq, xk, out);
}

// Round 2
// 206.339 us; speedup vs baseline: 3.7133x; 3.7133x over previous
//
#include <hip/hip_runtime.h>

// MoV3D: 3D local attention, window +-2 (125 offsets), B=2 C=32 H=W=D=48, 4 heads x 8 ch.
// LDS-tiled: block = 4x4x16 voxel tile (256 threads), halo k-tile 8x8x24 (z padded
// 20->24 for 2-way-free banks) staged per head-chunk (8 channels, c = 4k+h) = 48 KB.
// OOB offsets: addresses clamped, weight forced to 0 (== reference -1000 -> exp underflow).

#define S_PLANE 2304      // 48*48
#define S_CHAN 110592     // 48*48*48
#define NCH 32
#define NH 4
#define HD 8
#define TX 4
#define TY 4
#define TZ 16
#define HX 8
#define HY 8
#define HZ 24             // 20 used + 4 pad (banks: ty-group stride 24 -> exact 2-way, free)
#define KSTR (HX*HY*HZ)   // 1536 floats per channel slice

__global__ __launch_bounds__(256, 3) void mov3d_kernel(
    const float* __restrict__ xq, const float* __restrict__ xk,
    float* __restrict__ out)
{
    __shared__ float klds[HD * KSTR];   // 12288 floats = 48 KB

    const int tid = threadIdx.x;
    const int tz = tid & 15;
    const int ty = (tid >> 4) & 3;
    const int tx = tid >> 6;

    int blk = blockIdx.x;
    const int zt = blk % 3;  blk /= 3;
    const int yt = blk % 12; blk /= 12;
    const int xt = blk % 12;
    const int b  = blk / 12;          // 0..1

    const int x0 = xt * TX, y0 = yt * TY, z0 = zt * TZ;
    const int x = x0 + tx, y = y0 + ty, z = z0 + tz;
    const unsigned sp = (unsigned)(x * S_PLANE + y * 48 + z);
    const unsigned bbase = (unsigned)b * (NCH * S_CHAN);

    const float scale = 0.35355339059327373f;   // 8^-0.5

    bool vz[5];
#pragma unroll
    for (int j = 0; j < 5; ++j) vz[j] = (unsigned)(z + j - 2) < 48u;

    float ox = 0.f, oy = 0.f, oz = 0.f;

    // staging walk: flat element e = tid + 256*i over [0, 12288); row = e/24, lz = e%24
    const int lz_init  = tid % HZ;
    const int row_init = tid / HZ;

    for (int h = 0; h < NH; ++h) {
        // q for this head's 8 channels (independent of LDS; issued early)
        float qh[HD];
#pragma unroll
        for (int k = 0; k < HD; ++k)
            qh[k] = xq[bbase + (unsigned)((4 * k + h) * S_CHAN) + sp] * scale;

        __syncthreads();   // previous head's compute done before overwriting LDS
        {
            int lz = lz_init, row = row_init, waddr = tid;
#pragma unroll 4
            for (int i = 0; i < 48; ++i) {
                int ly = row & 7;
                int lx = (row >> 3) & 7;
                int k  = row >> 6;
                int gx = min(max(x0 - 2 + lx, 0), 47);
                int gy = min(max(y0 - 2 + ly, 0), 47);
                int gz = min(max(z0 - 2 + lz, 0), 47);
                int c  = 4 * k + h;
                klds[waddr] = xk[bbase + (unsigned)(c * S_CHAN)
                                       + (unsigned)(gx * S_PLANE + gy * 48 + gz)];
                waddr += 256;
                lz += 16; row += 10;
                if (lz >= HZ) { lz -= HZ; row += 1; }   // 256 = 10*24 + 16
            }
        }
        __syncthreads();

        float l = 0.f, axv = 0.f, ayv = 0.f, azv = 0.f;
        const float* base0 = &klds[(tx + 2) * (HY * HZ) + (ty + 2) * HZ + tz];

        for (int dx = -2; dx <= 2; ++dx) {
            bool vx = (unsigned)(x + dx) < 48u;
            float fdx = (float)dx;
            for (int dy = -2; dy <= 2; ++dy) {
                bool vxy = vx && ((unsigned)(y + dy) < 48u);
                float fdy = (float)dy;
                const float* p0 = base0 + dx * (HY * HZ) + dy * HZ;

                float s0 = 0.f, s1 = 0.f, s2 = 0.f, s3 = 0.f, s4 = 0.f;
#pragma unroll
                for (int k = 0; k < HD; ++k) {
                    const float* p = p0 + k * KSTR;   // ds_read immediate offsets
                    float qv = qh[k];
                    s0 = fmaf(qv, p[0], s0);
                    s1 = fmaf(qv, p[1], s1);
                    s2 = fmaf(qv, p[2], s2);
                    s3 = fmaf(qv, p[3], s3);
                    s4 = fmaf(qv, p[4], s4);
                }
                float s[5] = {s0, s1, s2, s3, s4};
#pragma unroll
                for (int j = 0; j < 5; ++j) {
                    float w = (vxy && vz[j]) ? __expf(s[j]) : 0.f;
                    l += w;
                    axv = fmaf(w, fdx, axv);
                    ayv = fmaf(w, fdy, ayv);
                    azv = fmaf(w, (float)(j - 2), azv);
                }
            }
        }
        float r = 1.0f / l;
        ox = fmaf(axv, r, ox);
        oy = fmaf(ayv, r, oy);
        oz = fmaf(azv, r, oz);
    }

    const unsigned ob = (unsigned)b * (3 * S_CHAN);
    out[ob + 0u * S_CHAN + sp] = ox * 0.25f;
    out[ob + 1u * S_CHAN + sp] = oy * 0.25f;
    out[ob + 2u * S_CHAN + sp] = oz * 0.25f;
}

extern "C" void kernel_launch(void* const* d_in, const int* in_sizes, int n_in,
                              void* d_out, int out_size, void* d_ws, size_t ws_size,
                              hipStream_t stream) {
    const float* xq = (const float*)d_in[0];
    const float* xk = (const float*)d_in[1];
    float* out = (float*)d_out;
    // grid: b(2) * xt(12) * yt(12) * zt(3) = 864 blocks of 256 threads
    mov3d_kernel<<<864, 256, 0, stream>>>(xq, xk, out);
}

// Round 3
// 100.985 us; speedup vs baseline: 7.5872x; 2.0433x over previous
//
#include <hip/hip_runtime.h>

// MoV3D: 3D local attention, window +-2 (125 offsets), B=2 C=32 H=W=D=48, 4 heads x 8 ch.
// Tile 4x8x16 voxels, 2 z-voxels per thread (256 threads). K halo staged per head
// (8 channels) via global_load_lds into 60KB LDS, layout [k][lx][ly][lz=20] (linear,
// conflict-free b64 reads: 20*ty+2*tz puts exactly 4 words/bank). Scores in log2
// domain (q prescaled by scale*log2e) -> 1-instr exp2. OOB: score forced to -16384
// -> exp2 == 0, matching reference's -1000 -> softmax underflow.

#define S_PLANE 2304      // 48*48
#define S_CHAN 110592     // 48*48*48
#define NH 4
#define HD 8
#define ROWSTR 20         // ly stride (floats)
#define XSTR 240          // lx stride = 12*20
#define KSTR 1920         // channel stride = 8*240
#define LDS_FLOATS (HD * KSTR)   // 15360 floats = 60 KB

__device__ __forceinline__ void gl_lds(const float* g, float* l) {
    __builtin_amdgcn_global_load_lds(
        (const __attribute__((address_space(1))) void*)g,
        (__attribute__((address_space(3))) void*)l, 4, 0, 0);
}

__global__ __launch_bounds__(256, 2) void mov3d_kernel(
    const float* __restrict__ xq, const float* __restrict__ xk,
    float* __restrict__ out)
{
    __shared__ float klds[LDS_FLOATS];

    const int tid = threadIdx.x;
    const int tz = tid & 7;           // 8 z-threads (2 voxels each)
    const int ty = (tid >> 3) & 7;    // 8
    const int tx = tid >> 6;          // 4

    int blk = blockIdx.x;             // 432 = 3(z) * 6(y) * 12(x) * 2(b)
    const int zt = blk % 3;  blk /= 3;
    const int yt = blk % 6;  blk /= 6;
    const int xt = blk % 12;
    const int b  = blk / 12;

    const int x0 = xt * 4, y0 = yt * 8, z0 = zt * 16;
    const int x = x0 + tx, y = y0 + ty, zb = z0 + 2 * tz;
    const unsigned spA = (unsigned)(x * S_PLANE + y * 48 + zb);
    const unsigned bbase = (unsigned)b * (32 * S_CHAN);

    // q prescale: hd^-0.5 * log2(e)  (scores kept in log2 domain)
    const float QSCALE = 0.35355339059327373f * 1.4426950408889634f;

    // staging spatial offsets: e = i*256+tid over [0,15360) per 8-ch chunk;
    // e < 1920 per channel; i=7 tail uses tid<128 (waves 0,1) only.
    unsigned gsp[8];
#pragma unroll
    for (int i = 0; i < 8; ++i) {
        const int e = i * 256 + tid;
        const int lx = e / XSTR;
        const int r  = e - lx * XSTR;
        const int ly = r / ROWSTR;
        const int lz = r - ly * ROWSTR;
        const int gx = min(max(x0 - 2 + lx, 0), 47);
        const int gy = min(max(y0 - 2 + ly, 0), 47);
        const int gz = min(max(z0 - 2 + lz, 0), 47);
        gsp[i] = (unsigned)(gx * S_PLANE + gy * 48 + gz);
    }

    // z-window validity: window slot u covers gz = zb-2+u; voxelA uses u=j, voxelB u=j+1
    bool vu[6];
#pragma unroll
    for (int u = 0; u < 6; ++u) vu[u] = (unsigned)(zb - 2 + u) < 48u;

    float oxA = 0.f, oyA = 0.f, ozA = 0.f;
    float oxB = 0.f, oyB = 0.f, ozB = 0.f;

    for (int h = 0; h < NH; ++h) {
        // q for this head's 8 channels, both voxels (consecutive z -> float2)
        float2 qv[HD];
#pragma unroll
        for (int k = 0; k < HD; ++k) {
            float2 t = *(const float2*)&xq[bbase + (unsigned)((4 * k + h) * S_CHAN) + spA];
            qv[k].x = t.x * QSCALE;
            qv[k].y = t.y * QSCALE;
        }

        __syncthreads();   // previous head's compute done before LDS overwrite
#pragma unroll
        for (int k = 0; k < HD; ++k) {
            const float* gch = xk + bbase + (unsigned)((4 * k + h) * S_CHAN);
#pragma unroll
            for (int i = 0; i < 8; ++i) {
                if (i < 7 || tid < 128)
                    gl_lds(gch + gsp[i], &klds[k * KSTR + i * 256 + tid]);
            }
        }
        __syncthreads();

        float lA = 0.f, axA = 0.f, ayA = 0.f, azA = 0.f;
        float lB = 0.f, axB = 0.f, ayB = 0.f, azB = 0.f;
        const float* pbase = &klds[(tx + 2) * XSTR + (ty + 2) * ROWSTR + 2 * tz];
        const float NEG = -16384.f;   // exp2 -> exactly 0

#pragma unroll
        for (int dx = -2; dx <= 2; ++dx) {
            const bool vx = (unsigned)(x + dx) < 48u;
            const float fdx = (float)dx;
#pragma unroll
            for (int dy = -2; dy <= 2; ++dy) {
                const bool vxy = vx && ((unsigned)(y + dy) < 48u);
                const float fdy = (float)dy;
                const float* p0 = pbase + dx * XSTR + dy * ROWSTR;

                float sA0 = 0.f, sA1 = 0.f, sA2 = 0.f, sA3 = 0.f, sA4 = 0.f;
                float sB0 = 0.f, sB1 = 0.f, sB2 = 0.f, sB3 = 0.f, sB4 = 0.f;
#pragma unroll
                for (int k = 0; k < HD; ++k) {
                    const float* pk = p0 + k * KSTR;
                    const float2 w01 = *(const float2*)(pk);
                    const float2 w23 = *(const float2*)(pk + 2);
                    const float2 w45 = *(const float2*)(pk + 4);
                    const float qa = qv[k].x, qb = qv[k].y;
                    sA0 = fmaf(qa, w01.x, sA0);
                    sA1 = fmaf(qa, w01.y, sA1);
                    sA2 = fmaf(qa, w23.x, sA2);
                    sA3 = fmaf(qa, w23.y, sA3);
                    sA4 = fmaf(qa, w45.x, sA4);
                    sB0 = fmaf(qb, w01.y, sB0);
                    sB1 = fmaf(qb, w23.x, sB1);
                    sB2 = fmaf(qb, w23.y, sB2);
                    sB3 = fmaf(qb, w45.x, sB3);
                    sB4 = fmaf(qb, w45.y, sB4);
                }

                const float eA0 = exp2f((vxy && vu[0]) ? sA0 : NEG);
                const float eA1 = exp2f((vxy && vu[1]) ? sA1 : NEG);
                const float eA2 = exp2f((vxy && vu[2]) ? sA2 : NEG);
                const float eA3 = exp2f((vxy && vu[3]) ? sA3 : NEG);
                const float eA4 = exp2f((vxy && vu[4]) ? sA4 : NEG);
                const float eB0 = exp2f((vxy && vu[1]) ? sB0 : NEG);
                const float eB1 = exp2f((vxy && vu[2]) ? sB1 : NEG);
                const float eB2 = exp2f((vxy && vu[3]) ? sB2 : NEG);
                const float eB3 = exp2f((vxy && vu[4]) ? sB3 : NEG);
                const float eB4 = exp2f((vxy && vu[5]) ? sB4 : NEG);

                const float wsA = ((eA0 + eA1) + (eA2 + eA3)) + eA4;
                const float wsB = ((eB0 + eB1) + (eB2 + eB3)) + eB4;
                lA += wsA;  lB += wsB;
                axA = fmaf(fdx, wsA, axA);  axB = fmaf(fdx, wsB, axB);
                ayA = fmaf(fdy, wsA, ayA);  ayB = fmaf(fdy, wsB, ayB);
                azA += fmaf(2.f, eA4 - eA0, eA3 - eA1);
                azB += fmaf(2.f, eB4 - eB0, eB3 - eB1);
            }
        }
        const float rA = 1.0f / lA;
        const float rB = 1.0f / lB;
        oxA = fmaf(axA, rA, oxA);  oxB = fmaf(axB, rB, oxB);
        oyA = fmaf(ayA, rA, oyA);  oyB = fmaf(ayB, rB, oyB);
        ozA = fmaf(azA, rA, ozA);  ozB = fmaf(azB, rB, ozB);
    }

    const unsigned ob = (unsigned)b * (3 * S_CHAN);
    float2 o;
    o.x = oxA * 0.25f; o.y = oxB * 0.25f;
    *(float2*)&out[ob + 0u * S_CHAN + spA] = o;
    o.x = oyA * 0.25f; o.y = oyB * 0.25f;
    *(float2*)&out[ob + 1u * S_CHAN + spA] = o;
    o.x = ozA * 0.25f; o.y = ozB * 0.25f;
    *(float2*)&out[ob + 2u * S_CHAN + spA] = o;
}

extern "C" void kernel_launch(void* const* d_in, const int* in_sizes, int n_in,
                              void* d_out, int out_size, void* d_ws, size_t ws_size,
                              hipStream_t stream) {
    const float* xq = (const float*)d_in[0];
    const float* xk = (const float*)d_in[1];
    float* out = (float*)d_out;
    // grid: 3(z) * 6(y) * 12(x) * 2(b) = 432 blocks of 256 threads
    mov3d_kernel<<<432, 256, 0, stream>>>(xq, xk, out);
}

// Round 4
// 98.915 us; speedup vs baseline: 7.7460x; 1.0209x over previous
//
#include <hip/hip_runtime.h>

// MoV3D: 3D local attention, window +-2 (125 offsets), B=2 C=32 H=W=D=48, 4 heads x 8 ch.
// Head-split grid: each block = (b, head, 4x8x16 tile), 2 z-voxels per thread (256 thr).
// K halo (8 channels, c=4k+h) staged once per block via global_load_lds into 60KB LDS,
// layout [k][lx=12][ly=12->wait 8x12x20] linear; ONE barrier per block. Heads combined
// with fp32 atomicAdd into zeroed d_out. Scores in log2 domain -> 1-instr exp2.
// OOB: score forced to -16384 -> exp2==0 (== reference -1000 softmax underflow).

#define S_PLANE 2304      // 48*48
#define S_CHAN 110592     // 48*48*48
#define HD 8
#define ROWSTR 20         // lz extent (16 tile + 4 halo)
#define XSTR 240          // lx stride = 12*20 (ly=12: 8 tile + 4 halo)
#define KSTR 1920         // channel stride = 8*240
#define LDS_FLOATS (HD * KSTR)   // 15360 floats = 60 KB

__device__ __forceinline__ void gl_lds(const float* g, float* l) {
    __builtin_amdgcn_global_load_lds(
        (const __attribute__((address_space(1))) void*)g,
        (__attribute__((address_space(3))) void*)l, 4, 0, 0);
}

__global__ __launch_bounds__(256, 2) void mov3d_kernel(
    const float* __restrict__ xq, const float* __restrict__ xk,
    float* __restrict__ out)
{
    __shared__ float klds[LDS_FLOATS];

    const int tid = threadIdx.x;
    const int tz = tid & 7;           // 8 z-threads (2 voxels each)
    const int ty = (tid >> 3) & 7;    // 8
    const int tx = tid >> 6;          // 4

    int blk = blockIdx.x;             // 1728 = 4(h) * [2(b) * 12(xt) * 6(yt) * 3(zt)]
    const int h = blk / 432;
    int rem = blk - h * 432;
    const int zt = rem % 3;  rem /= 3;
    const int yt = rem % 6;  rem /= 6;
    const int xt = rem % 12;
    const int b  = rem / 12;

    const int x0 = xt * 4, y0 = yt * 8, z0 = zt * 16;
    const int x = x0 + tx, y = y0 + ty, zb = z0 + 2 * tz;
    const unsigned spA = (unsigned)(x * S_PLANE + y * 48 + zb);
    const unsigned bbase = (unsigned)b * (32 * S_CHAN);

    // q prescale: hd^-0.5 * log2(e)  (scores kept in log2 domain)
    const float QSCALE = 0.35355339059327373f * 1.4426950408889634f;

    // staging spatial offsets: e = i*256+tid over [0,1920) per channel; i=7: tid<128.
    unsigned gsp[8];
#pragma unroll
    for (int i = 0; i < 8; ++i) {
        const int e = i * 256 + tid;
        const int lx = e / XSTR;
        const int r  = e - lx * XSTR;
        const int ly = r / ROWSTR;
        const int lz = r - ly * ROWSTR;
        const int gx = min(max(x0 - 2 + lx, 0), 47);
        const int gy = min(max(y0 - 2 + ly, 0), 47);
        const int gz = min(max(z0 - 2 + lz, 0), 47);
        gsp[i] = (unsigned)(gx * S_PLANE + gy * 48 + gz);
    }

    // q for this head's 8 channels, both voxels (consecutive z -> float2); issue early,
    // completes with the staging drain at the barrier.
    float2 qv[HD];
#pragma unroll
    for (int k = 0; k < HD; ++k) {
        float2 t = *(const float2*)&xq[bbase + (unsigned)((4 * k + h) * S_CHAN) + spA];
        qv[k].x = t.x * QSCALE;
        qv[k].y = t.y * QSCALE;
    }

#pragma unroll
    for (int k = 0; k < HD; ++k) {
        const float* gch = xk + bbase + (unsigned)((4 * k + h) * S_CHAN);
#pragma unroll
        for (int i = 0; i < 8; ++i) {
            if (i < 7 || tid < 128)
                gl_lds(gch + gsp[i], &klds[k * KSTR + i * 256 + tid]);
        }
    }
    __syncthreads();   // the only barrier: stage complete

    // z-window validity: slot u covers gz = zb-2+u; voxelA uses u=j, voxelB u=j+1
    bool vu[6];
#pragma unroll
    for (int u = 0; u < 6; ++u) vu[u] = (unsigned)(zb - 2 + u) < 48u;

    float lA = 0.f, axA = 0.f, ayA = 0.f, azA = 0.f;
    float lB = 0.f, axB = 0.f, ayB = 0.f, azB = 0.f;
    const float* pbase = &klds[(tx + 2) * XSTR + (ty + 2) * ROWSTR + 2 * tz];
    const float NEG = -16384.f;   // exp2 -> exactly 0

    __builtin_amdgcn_s_setprio(1);   // resident co-block is staging; favor compute wave
#pragma unroll
    for (int dx = -2; dx <= 2; ++dx) {
        const bool vx = (unsigned)(x + dx) < 48u;
        const float fdx = (float)dx;
#pragma unroll
        for (int dy = -2; dy <= 2; ++dy) {
            const bool vxy = vx && ((unsigned)(y + dy) < 48u);
            const float fdy = (float)dy;
            const float* p0 = pbase + dx * XSTR + dy * ROWSTR;

            float sA0 = 0.f, sA1 = 0.f, sA2 = 0.f, sA3 = 0.f, sA4 = 0.f;
            float sB0 = 0.f, sB1 = 0.f, sB2 = 0.f, sB3 = 0.f, sB4 = 0.f;
#pragma unroll
            for (int k = 0; k < HD; ++k) {
                const float* pk = p0 + k * KSTR;   // compile-time ds offsets
                const float2 w01 = *(const float2*)(pk);
                const float2 w23 = *(const float2*)(pk + 2);
                const float2 w45 = *(const float2*)(pk + 4);
                const float qa = qv[k].x, qb = qv[k].y;
                sA0 = fmaf(qa, w01.x, sA0);
                sA1 = fmaf(qa, w01.y, sA1);
                sA2 = fmaf(qa, w23.x, sA2);
                sA3 = fmaf(qa, w23.y, sA3);
                sA4 = fmaf(qa, w45.x, sA4);
                sB0 = fmaf(qb, w01.y, sB0);
                sB1 = fmaf(qb, w23.x, sB1);
                sB2 = fmaf(qb, w23.y, sB2);
                sB3 = fmaf(qb, w45.x, sB3);
                sB4 = fmaf(qb, w45.y, sB4);
            }

            const float eA0 = exp2f((vxy && vu[0]) ? sA0 : NEG);
            const float eA1 = exp2f((vxy && vu[1]) ? sA1 : NEG);
            const float eA2 = exp2f((vxy && vu[2]) ? sA2 : NEG);
            const float eA3 = exp2f((vxy && vu[3]) ? sA3 : NEG);
            const float eA4 = exp2f((vxy && vu[4]) ? sA4 : NEG);
            const float eB0 = exp2f((vxy && vu[1]) ? sB0 : NEG);
            const float eB1 = exp2f((vxy && vu[2]) ? sB1 : NEG);
            const float eB2 = exp2f((vxy && vu[3]) ? sB2 : NEG);
            const float eB3 = exp2f((vxy && vu[4]) ? sB3 : NEG);
            const float eB4 = exp2f((vxy && vu[5]) ? sB4 : NEG);

            const float wsA = ((eA0 + eA1) + (eA2 + eA3)) + eA4;
            const float wsB = ((eB0 + eB1) + (eB2 + eB3)) + eB4;
            lA += wsA;  lB += wsB;
            axA = fmaf(fdx, wsA, axA);  axB = fmaf(fdx, wsB, axB);
            ayA = fmaf(fdy, wsA, ayA);  ayB = fmaf(fdy, wsB, ayB);
            azA += fmaf(2.f, eA4 - eA0, eA3 - eA1);
            azB += fmaf(2.f, eB4 - eB0, eB3 - eB1);
        }
    }
    __builtin_amdgcn_s_setprio(0);

    const float rA = 0.25f / lA;
    const float rB = 0.25f / lB;
    const unsigned ob = (unsigned)b * (3 * S_CHAN);
    atomicAdd(&out[ob + 0u * S_CHAN + spA],     axA * rA);
    atomicAdd(&out[ob + 0u * S_CHAN + spA + 1], axB * rB);
    atomicAdd(&out[ob + 1u * S_CHAN + spA],     ayA * rA);
    atomicAdd(&out[ob + 1u * S_CHAN + spA + 1], ayB * rB);
    atomicAdd(&out[ob + 2u * S_CHAN + spA],     azA * rA);
    atomicAdd(&out[ob + 2u * S_CHAN + spA + 1], azB * rB);
}

extern "C" void kernel_launch(void* const* d_in, const int* in_sizes, int n_in,
                              void* d_out, int out_size, void* d_ws, size_t ws_size,
                              hipStream_t stream) {
    const float* xq = (const float*)d_in[0];
    const float* xk = (const float*)d_in[1];
    float* out = (float*)d_out;
    // zero output (heads accumulate via atomicAdd); memset node is graph-capturable
    hipMemsetAsync(out, 0, (size_t)out_size * sizeof(float), stream);
    // grid: 4(head) * 2(b) * 12(xt) * 6(yt) * 3(zt) = 1728 blocks of 256 threads
    mov3d_kernel<<<1728, 256, 0, stream>>>(xq, xk, out);
}